// Round 6
// baseline (245.499 us; speedup 1.0000x reference)
//
#include <hip/hip_runtime.h>

#define NDIM 4096
#define B_LG 256
#define B_SM 256
#define N_WID 128
#define R_LG 64
#define R_SM 16
#define BLOCK 512
#define MAXB 256           // bucket capacity per wid
#define MG 4               // max batches fused per pass over A
#define PF 8               // float4 loads in flight per thread (128 B)
#define OUT_SIZE (B_LG * R_LG + B_SM * R_SM)

// d_ws ints: [0..128) cnt_l | [128..256) cnt_s | buckets
#define WS_CNT_L 0
#define WS_CNT_S 128
#define WS_BKT_L 256
#define WS_BKT_S (256 + N_WID * MAXB)

// ------------- kernel 1: bucket batches by wid + zero out -------------------
__global__ __launch_bounds__(BLOCK)
void setup_kernel(const int* __restrict__ wids_l,
                  const int* __restrict__ wids_s,
                  int* __restrict__ ws,
                  float* __restrict__ out)
{
    __shared__ int cl[N_WID], cs[N_WID];
    const int t = threadIdx.x;
    if (t < N_WID) { cl[t] = 0; cs[t] = 0; }
    __syncthreads();
    if (t < B_LG) {
        const int w = wids_l[t];
        const int s = atomicAdd(&cl[w], 1);
        ws[WS_BKT_L + w * MAXB + s] = t;
    } else if (t < B_LG + B_SM) {
        const int b = t - B_LG;
        const int w = wids_s[b];
        const int s = atomicAdd(&cs[w], 1);
        ws[WS_BKT_S + w * MAXB + s] = b;
    }
    __syncthreads();
    if (t < N_WID) { ws[WS_CNT_L + t] = cl[t]; ws[WS_CNT_S + t] = cs[t]; }
    for (int i = t; i < OUT_SIZE; i += BLOCK) out[i] = 0.0f;
}

// ------------- kernel 2: grouped chunk-GEMV ---------------------------------
// One 512-thread block streams a DCH-row chunk of A[wid] exactly once while
// accumulating up to M batches' partial dots; chunks combine via atomicAdd.
// PF=8 float4 loads in flight per thread -> latency-saturating MLP.
template<int R, int M, int DCH>
__device__ __forceinline__ void gemv_chunk(
    const float* __restrict__ x,      // x rows base for this class
    const float* __restrict__ Ab,     // A[wid]
    float* __restrict__ outb,         // out base for this class
    const int* __restrict__ batches,  // M batch indices (uniform scalar reads)
    int d0,                           // d offset of this chunk
    float* __restrict__ xs,           // LDS [MG][DCH]
    float* __restrict__ red)          // LDS [8][16][4]
{
    constexpr int LPR  = R / 4;         // lanes per A-row: 16 (R=64) or 4 (R=16)
    constexpr int ROWS = BLOCK / LPR;   // A-rows per float4-iter: 32 or 128
    constexpr int IT   = DCH / ROWS;    // 32 (large) or 16 (small)

    const int t = threadIdx.x;

    int rows[M];
#pragma unroll
    for (int m = 0; m < M; ++m) rows[m] = batches[m];  // uniform -> s_load

    __syncthreads();  // previous group's xs reads finished
    // stage M x-row chunks (static m -> no dynamic reg indexing)
#pragma unroll
    for (int m = 0; m < M; ++m)
        for (int i = t; i < DCH / 4; i += BLOCK)
            reinterpret_cast<float4*>(xs + m * DCH)[i] =
                reinterpret_cast<const float4*>(x + (size_t)rows[m] * NDIM + d0)[i];
    __syncthreads();

    const int d_sub  = t / LPR;
    const int r_base = (t % LPR) * 4;
    const float* Abt = Ab + ((size_t)d0 + d_sub) * R + r_base;

    float acc[M][4];
#pragma unroll
    for (int m = 0; m < M; ++m)
#pragma unroll
        for (int j = 0; j < 4; ++j) acc[m][j] = 0.0f;

    for (int ig = 0; ig < IT; ig += PF) {
        float4 pf[PF];
#pragma unroll
        for (int p = 0; p < PF; ++p)
            pf[p] = *reinterpret_cast<const float4*>(Abt + (size_t)(ig + p) * ROWS * R);
#pragma unroll
        for (int p = 0; p < PF; ++p) {
            const int d = (ig + p) * ROWS + d_sub;
#pragma unroll
            for (int m = 0; m < M; ++m) {
                const float xv = xs[m * DCH + d];
                acc[m][0] = fmaf(xv, pf[p].x, acc[m][0]);
                acc[m][1] = fmaf(xv, pf[p].y, acc[m][1]);
                acc[m][2] = fmaf(xv, pf[p].z, acc[m][2]);
                acc[m][3] = fmaf(xv, pf[p].w, acc[m][3]);
            }
        }
    }

    // reduce: shuffle within wave, LDS across 8 waves, atomicAdd per chunk
    const int wave = t >> 6;
    const int lane = t & 63;
#pragma unroll
    for (int m = 0; m < M; ++m)
#pragma unroll
        for (int off = 32; off >= LPR; off >>= 1)
#pragma unroll
            for (int j = 0; j < 4; ++j)
                acc[m][j] += __shfl_down(acc[m][j], off, 64);

#pragma unroll
    for (int m = 0; m < M; ++m) {
        __syncthreads();
        if (lane < LPR)
#pragma unroll
            for (int j = 0; j < 4; ++j) red[(wave * 16 + lane) * 4 + j] = acc[m][j];
        __syncthreads();
        if (t < R) {
            const int rl = t / 4, j = t % 4;
            float v = 0.0f;
#pragma unroll
            for (int w = 0; w < 8; ++w) v += red[(w * 16 + rl) * 4 + j];
            atomicAdd(outb + (size_t)rows[m] * R + t, v);
        }
    }
}

template<int R, int DCH>
__device__ __forceinline__ void run_wid_chunk(
    const float* x, const float* Ab, float* outb,
    const int* bucket, int count, int d0,
    float* xs, float* red)
{
    for (int g = 0; g < count; g += MG) {
        const int M = min(MG, count - g);
        const int* b = bucket + g;
        switch (M) {
            case 1: gemv_chunk<R, 1, DCH>(x, Ab, outb, b, d0, xs, red); break;
            case 2: gemv_chunk<R, 2, DCH>(x, Ab, outb, b, d0, xs, red); break;
            case 3: gemv_chunk<R, 3, DCH>(x, Ab, outb, b, d0, xs, red); break;
            default: gemv_chunk<R, 4, DCH>(x, Ab, outb, b, d0, xs, red); break;
        }
    }
}

// Grid: 768 blocks. [0,512): large wids in d-quarters (256 KB of A each).
// [512,768): small wids in d-halves (128 KB each). 3 blocks/CU resident.
__global__ __launch_bounds__(BLOCK, 6)
void SequentialLoraA_kernel(const float* __restrict__ x,
                            const float* __restrict__ Al,
                            const float* __restrict__ As,
                            float* __restrict__ out,
                            const int* __restrict__ ws)
{
    __shared__ float xs[MG * 2048];      // 32 KB
    __shared__ float red[8 * 16 * 4];    // 2 KB

    const int blk = blockIdx.x;
    if (blk < 4 * N_WID) {
        const int wid = blk >> 2;
        const int d0  = (blk & 3) * 1024;
        run_wid_chunk<R_LG, 1024>(x,
                                  Al + (size_t)wid * NDIM * R_LG,
                                  out,
                                  ws + WS_BKT_L + wid * MAXB,
                                  ws[WS_CNT_L + wid], d0,
                                  xs, red);
    } else {
        const int b2  = blk - 4 * N_WID;
        const int wid = b2 >> 1;
        const int d0  = (b2 & 1) * 2048;
        run_wid_chunk<R_SM, 2048>(x + (size_t)B_LG * NDIM,
                                  As + (size_t)wid * NDIM * R_SM,
                                  out + (size_t)B_LG * R_LG,
                                  ws + WS_BKT_S + wid * MAXB,
                                  ws[WS_CNT_S + wid], d0,
                                  xs, red);
    }
}

extern "C" void kernel_launch(void* const* d_in, const int* in_sizes, int n_in,
                              void* d_out, int out_size, void* d_ws, size_t ws_size,
                              hipStream_t stream) {
    const float* x      = (const float*)d_in[0];
    const int*   wids_l = (const int*)d_in[1];
    const int*   wids_s = (const int*)d_in[2];
    const float* Al     = (const float*)d_in[3];
    const float* As     = (const float*)d_in[4];
    float* out = (float*)d_out;
    int*   ws  = (int*)d_ws;

    setup_kernel<<<1, BLOCK, 0, stream>>>(wids_l, wids_s, ws, out);
    SequentialLoraA_kernel<<<6 * N_WID, BLOCK, 0, stream>>>(x, Al, As, out, ws);
}

// Round 8
// 225.612 us; speedup vs baseline: 1.0881x; 1.0881x over previous
//
#include <hip/hip_runtime.h>

#define NDIM 4096
#define B_LG 256
#define B_SM 256
#define N_WID 128
#define R_LG 64
#define R_SM 16
#define BLOCK 512
#define MAXB 256           // bucket capacity per wid
#define PF 8               // float4 loads per software-pipeline group
#define OUT_SIZE (B_LG * R_LG + B_SM * R_SM)

typedef float floatv4 __attribute__((ext_vector_type(4)));  // nt-load-compatible

// d_ws ints: [0..128) cnt_l | [128..256) cnt_s | buckets
#define WS_CNT_L 0
#define WS_CNT_S 128
#define WS_BKT_L 256
#define WS_BKT_S (256 + N_WID * MAXB)

// ------------- kernel 1: bucket batches by wid + zero out -------------------
__global__ __launch_bounds__(BLOCK)
void setup_kernel(const int* __restrict__ wids_l,
                  const int* __restrict__ wids_s,
                  int* __restrict__ ws,
                  float* __restrict__ out)
{
    __shared__ int cl[N_WID], cs[N_WID];
    const int t = threadIdx.x;
    if (t < N_WID) { cl[t] = 0; cs[t] = 0; }
    __syncthreads();
    if (t < B_LG) {
        const int w = wids_l[t];
        const int s = atomicAdd(&cl[w], 1);
        ws[WS_BKT_L + w * MAXB + s] = t;
    } else if (t < B_LG + B_SM) {
        const int b = t - B_LG;
        const int w = wids_s[b];
        const int s = atomicAdd(&cs[w], 1);
        ws[WS_BKT_S + w * MAXB + s] = b;
    }
    __syncthreads();
    if (t < N_WID) { ws[WS_CNT_L + t] = cl[t]; ws[WS_CNT_S + t] = cs[t]; }
    for (int i = t; i < OUT_SIZE; i += BLOCK) out[i] = 0.0f;
}

// ------------- kernel 2: grouped chunk-GEMV, straight-line pipelined --------
// One 512-thread block streams a DCH-row chunk of A[wid] exactly once (non-
// temporal, fully unrolled so the scheduler keeps loads in flight across FMA
// groups) while accumulating M batches' partial dots. Chunks combine via
// atomicAdd into zero-initialized out.
template<int R, int M, int DCH>
__device__ __forceinline__ void gemv_chunk(
    const float* __restrict__ x,      // x rows base for this class
    const float* __restrict__ Ab,     // A[wid]
    float* __restrict__ outb,         // out base for this class
    const int* __restrict__ batches,  // M batch indices (uniform scalar reads)
    int d0,                           // d offset of this chunk
    float* __restrict__ xs,           // LDS, >= M*DCH floats
    float* __restrict__ red)          // LDS [8][16][4]
{
    constexpr int LPR  = R / 4;         // lanes per A-row: 16 (R=64) or 4 (R=16)
    constexpr int ROWS = BLOCK / LPR;   // A-rows per float4-iter: 32 or 128
    constexpr int IT   = DCH / ROWS;    // 32 (large) or 16 (small)
    constexpr int NG   = IT / PF;       // 4 or 2 pipeline groups

    const int t = threadIdx.x;

    int rows[M];
#pragma unroll
    for (int m = 0; m < M; ++m) rows[m] = batches[m];  // uniform -> s_load

    __syncthreads();  // previous group's xs reads finished
#pragma unroll
    for (int m = 0; m < M; ++m)
        for (int i = t; i < DCH / 4; i += BLOCK)
            reinterpret_cast<float4*>(xs + m * DCH)[i] =
                reinterpret_cast<const float4*>(x + (size_t)rows[m] * NDIM + d0)[i];
    __syncthreads();

    const int d_sub  = t / LPR;
    const int r_base = (t % LPR) * 4;
    const float* Abt = Ab + ((size_t)d0 + d_sub) * R + r_base;

    float acc[M][4];
#pragma unroll
    for (int m = 0; m < M; ++m)
#pragma unroll
        for (int j = 0; j < 4; ++j) acc[m][j] = 0.0f;

    // Fully unrolled: NG groups of PF nontemporal float4 loads + FMAs in one
    // straight-line block; the scheduler overlaps group g+1 loads with group
    // g FMAs (fine-grained vmcnt, no full drains).
#pragma unroll
    for (int g = 0; g < NG; ++g) {
        floatv4 buf[PF];
#pragma unroll
        for (int p = 0; p < PF; ++p)
            buf[p] = __builtin_nontemporal_load(
                reinterpret_cast<const floatv4*>(Abt + (size_t)(g * PF + p) * ROWS * R));
#pragma unroll
        for (int p = 0; p < PF; ++p) {
            const int d = (g * PF + p) * ROWS + d_sub;
#pragma unroll
            for (int m = 0; m < M; ++m) {
                const float xv = xs[m * DCH + d];
                acc[m][0] = fmaf(xv, buf[p].x, acc[m][0]);
                acc[m][1] = fmaf(xv, buf[p].y, acc[m][1]);
                acc[m][2] = fmaf(xv, buf[p].z, acc[m][2]);
                acc[m][3] = fmaf(xv, buf[p].w, acc[m][3]);
            }
        }
    }

    // reduce: shuffle within wave, LDS across 8 waves, atomicAdd per chunk
    const int wave = t >> 6;
    const int lane = t & 63;
#pragma unroll
    for (int m = 0; m < M; ++m)
#pragma unroll
        for (int off = 32; off >= LPR; off >>= 1)
#pragma unroll
            for (int j = 0; j < 4; ++j)
                acc[m][j] += __shfl_down(acc[m][j], off, 64);

#pragma unroll
    for (int m = 0; m < M; ++m) {
        __syncthreads();
        if (lane < LPR)
#pragma unroll
            for (int j = 0; j < 4; ++j) red[(wave * 16 + lane) * 4 + j] = acc[m][j];
        __syncthreads();
        if (t < R) {
            const int rl = t / 4, j = t % 4;
            float v = 0.0f;
#pragma unroll
            for (int w = 0; w < 8; ++w) v += red[(w * 16 + rl) * 4 + j];
            atomicAdd(outb + (size_t)rows[m] * R + t, v);
        }
    }
}

template<int R, int DCH, int MAXM>
__device__ __forceinline__ void run_wid_chunk(
    const float* x, const float* Ab, float* outb,
    const int* bucket, int count, int d0,
    float* xs, float* red)
{
    for (int g = 0; g < count; g += MAXM) {
        const int Mi = min(MAXM, count - g);
        const int* b = bucket + g;
        if (Mi == 1)      gemv_chunk<R, 1, DCH>(x, Ab, outb, b, d0, xs, red);
        else if (Mi == 2) gemv_chunk<R, 2, DCH>(x, Ab, outb, b, d0, xs, red);
        else if (Mi == 3) gemv_chunk<R, 3, DCH>(x, Ab, outb, b, d0, xs, red);
        else {
            if constexpr (MAXM > 3) {
                if (Mi == 4)      gemv_chunk<R, 4, DCH>(x, Ab, outb, b, d0, xs, red);
                else if (Mi == 5) gemv_chunk<R, 5, DCH>(x, Ab, outb, b, d0, xs, red);
                else              gemv_chunk<R, 6, DCH>(x, Ab, outb, b, d0, xs, red);
            }
        }
    }
}

// Grid: 768 blocks. [0,512): large wids in d-quarters (256 KB of A each, M<=6).
// [512,768): small wids in d-halves (128 KB each, M<=3).
__global__ __launch_bounds__(BLOCK, 4)
void SequentialLoraA_kernel(const float* __restrict__ x,
                            const float* __restrict__ Al,
                            const float* __restrict__ As,
                            float* __restrict__ out,
                            const int* __restrict__ ws)
{
    __shared__ float xs[6 * 1024];       // 24 KB (large: 6x1024, small: 3x2048)
    __shared__ float red[8 * 16 * 4];    // 2 KB

    const int blk = blockIdx.x;
    if (blk < 4 * N_WID) {
        const int wid = blk >> 2;
        const int d0  = (blk & 3) * 1024;
        run_wid_chunk<R_LG, 1024, 6>(x,
                                     Al + (size_t)wid * NDIM * R_LG,
                                     out,
                                     ws + WS_BKT_L + wid * MAXB,
                                     ws[WS_CNT_L + wid], d0,
                                     xs, red);
    } else {
        const int b2  = blk - 4 * N_WID;
        const int wid = b2 >> 1;
        const int d0  = (b2 & 1) * 2048;
        run_wid_chunk<R_SM, 2048, 3>(x + (size_t)B_LG * NDIM,
                                     As + (size_t)wid * NDIM * R_SM,
                                     out + (size_t)B_LG * R_LG,
                                     ws + WS_BKT_S + wid * MAXB,
                                     ws[WS_CNT_S + wid], d0,
                                     xs, red);
    }
}

extern "C" void kernel_launch(void* const* d_in, const int* in_sizes, int n_in,
                              void* d_out, int out_size, void* d_ws, size_t ws_size,
                              hipStream_t stream) {
    const float* x      = (const float*)d_in[0];
    const int*   wids_l = (const int*)d_in[1];
    const int*   wids_s = (const int*)d_in[2];
    const float* Al     = (const float*)d_in[3];
    const float* As     = (const float*)d_in[4];
    float* out = (float*)d_out;
    int*   ws  = (int*)d_ws;

    setup_kernel<<<1, BLOCK, 0, stream>>>(wids_l, wids_s, ws, out);
    SequentialLoraA_kernel<<<6 * N_WID, BLOCK, 0, stream>>>(x, Al, As, out, ws);
}